// Round 4
// baseline (361.844 us; speedup 1.0000x reference)
//
#include <hip/hip_runtime.h>

typedef unsigned short u16;
typedef short bf16x8 __attribute__((ext_vector_type(8)));
typedef float f32x4 __attribute__((ext_vector_type(4)));

__device__ __forceinline__ float bf2f(u16 x) { return __uint_as_float(((unsigned)x) << 16); }
__device__ __forceinline__ u16 f2bf(float f) {
    unsigned u = __float_as_uint(f);
    return (u16)((u + 0x7fffu + ((u >> 16) & 1u)) >> 16);
}
__device__ __forceinline__ float exp2_hw(float x) {
    float r;
    asm("v_exp_f32 %0, %1" : "=v"(r) : "v"(x));
    return r;
}
template <int CTRL>
__device__ __forceinline__ float dpp_add(float p) {
    int t = __builtin_amdgcn_update_dpp(0, __float_as_int(p), CTRL, 0xf, 0xf, true);
    return p + __int_as_float(t);
}

// ---------------- fused prep kernel ----------------
// block ranges: [0,c0) f32->bf16 cvt; [c0,c1) weight transpose; [c1,c2) post-MLP fuse;
// [c2,c3) edge count; [c3,c4) bias concat. All independent.

__global__ __launch_bounds__(256) void k_prep(const float* __restrict__ x,
                                              const float* __restrict__ W1l, const float* __restrict__ W1r,
                                              const float* __restrict__ W2l, const float* __restrict__ W2r,
                                              const float* __restrict__ b1l, const float* __restrict__ b1r,
                                              const float* __restrict__ b2l, const float* __restrict__ b2r,
                                              const float* __restrict__ Wp1, const float* __restrict__ bp1,
                                              const float* __restrict__ Wp2, const float* __restrict__ bp2,
                                              const int* __restrict__ ei,
                                              u16* __restrict__ Abuf, u16* __restrict__ WB1,
                                              u16* __restrict__ WB2, float* __restrict__ bc1,
                                              float* __restrict__ bc2, u16* __restrict__ Wpt,
                                              float* __restrict__ bpf, int* __restrict__ cnt,
                                              int N, int E, int c0, int c1, int c2, int c3) {
    int b = blockIdx.x;
    int tid = threadIdx.x;
    if (b < c0) {  // x -> bf16
        long i = ((long)b * 256 + tid) * 4;
        if (i + 3 < (long)N * 256) {
            float4 v = *(const float4*)(x + i);
            ushort4 w = {f2bf(v.x), f2bf(v.y), f2bf(v.z), f2bf(v.w)};
            *(ushort4*)(Abuf + i) = w;
        }
    } else if (b < c1) {  // weight transpose: WB = [Wl^T ; Wr^T] bf16
        int r = b - c0;
        int n = r & 255, m = r >> 8;
        const float* W = (m == 0) ? W1l : (m == 1) ? W1r : (m == 2) ? W2l : W2r;
        u16* dst = (m < 2) ? WB1 : WB2;
        dst[(size_t)((m & 1) * 256 + n) * 256 + tid] = f2bf(W[(size_t)tid * 256 + n]);
    } else if (b < c2) {  // fused post-MLP weight: Wpt[j][i] = bf16(sum_k Wp1[i][k]*Wp2[k][j])
        int j = b - c1;
        float a = 0.f;
        for (int k = 0; k < 64; ++k) a += Wp1[tid * 64 + k] * Wp2[k * 64 + j];
        Wpt[j * 256 + tid] = f2bf(a);
        if (tid == 0) {
            float bb = bp2[j];
            for (int k = 0; k < 64; ++k) bb += bp1[k] * Wp2[k * 64 + j];
            bpf[j] = bb;
        }
    } else if (b < c3) {  // degree count
        int e = (b - c2) * 256 + tid;
        if (e < E + N) {
            int dst = (e < E) ? ei[E + e] : (e - E);
            atomicAdd(cnt + dst, 1);
        }
    } else {  // bias concat
        int m = b - c3;
        const float* s = (m == 0) ? b1l : (m == 1) ? b1r : (m == 2) ? b2l : b2r;
        float* d = (m < 2) ? bc1 : bc2;
        d[(m & 1) * 256 + tid] = s[tid];
    }
}

// ---------------- CSR build ----------------

__global__ __launch_bounds__(256) void k_scan_block(const int* __restrict__ cnt,
                                                    int* __restrict__ rowptr,
                                                    int* __restrict__ bsums, int N) {
    __shared__ int sd[256];
    int tid = threadIdx.x;
    int base = blockIdx.x * 1024 + tid * 4;
    int v0 = (base + 0 < N) ? cnt[base + 0] : 0;
    int v1 = (base + 1 < N) ? cnt[base + 1] : 0;
    int v2 = (base + 2 < N) ? cnt[base + 2] : 0;
    int v3 = (base + 3 < N) ? cnt[base + 3] : 0;
    int ts = v0 + v1 + v2 + v3;
    sd[tid] = ts;
    __syncthreads();
    for (int ofs = 1; ofs < 256; ofs <<= 1) {
        int t = (tid >= ofs) ? sd[tid - ofs] : 0;
        __syncthreads();
        sd[tid] += t;
        __syncthreads();
    }
    int excl = sd[tid] - ts;
    if (base + 0 < N) rowptr[base + 0] = excl;
    if (base + 1 < N) rowptr[base + 1] = excl + v0;
    if (base + 2 < N) rowptr[base + 2] = excl + v0 + v1;
    if (base + 3 < N) rowptr[base + 3] = excl + v0 + v1 + v2;
    if (tid == 255) bsums[blockIdx.x] = sd[255];
}

__global__ void k_scan_bsums(int* __restrict__ bsums, int nb) {
    int l = threadIdx.x;
    int v = (l < nb) ? bsums[l] : 0;
    int x = v;
    for (int ofs = 1; ofs < 64; ofs <<= 1) {
        int t = __shfl_up(x, ofs);
        if (l >= ofs) x += t;
    }
    if (l < nb) bsums[l] = x - v;
}

__global__ __launch_bounds__(256) void k_finalize(int* __restrict__ rowptr,
                                                  const int* __restrict__ bscan,
                                                  int* __restrict__ cursor, int N, int EP) {
    int i = blockIdx.x * 256 + threadIdx.x;
    if (i < N) {
        int v = rowptr[i] + bscan[i >> 10];
        rowptr[i] = v;
        cursor[i] = v;
    } else if (i == N) {
        rowptr[N] = EP;
    }
}

__global__ __launch_bounds__(256) void k_scatter(const int* __restrict__ ei,
                                                 int* __restrict__ cursor,
                                                 int* __restrict__ csr, int E, int N) {
    int e = blockIdx.x * 256 + threadIdx.x;
    if (e < E + N) {
        int src, dst;
        if (e < E) { src = ei[e]; dst = ei[E + e]; }
        else       { src = e - E; dst = e - E; }
        int p = atomicAdd(cursor + dst, 1);
        csr[p] = src;
    }
}

// ---------------- B-panel-resident MFMA GEMM ----------------
// C[M,Nout] = A[M,256] @ Bt^T + bias.  A:[Mpad][256] bf16 row-major, Bt:[Nout][256] bf16.
// Block = 128 rows x BN cols. B panel (BN x 256) staged in LDS ONCE (XOR chunk swizzle),
// A streamed from global directly into MFMA fragments. One barrier per block.
// 8 waves (2 x 4): wave tile 64 x (NRF*16), NRF = BN/64.

template <int BN, int NRF, bool F32OUT>
__global__ __launch_bounds__(512) void k_gemm_bres(const u16* __restrict__ A,
                                                   const u16* __restrict__ Bt,
                                                   const float* __restrict__ bias,
                                                   void* __restrict__ out, int M, int Nout) {
    constexpr int K = 256;
    __shared__ __align__(16) u16 Bs[BN * K];
    const int tid = threadIdx.x;
    const int l = tid & 63;
    const int w = tid >> 6;            // 0..7
    const int wm = w >> 2, wn = w & 3; // 2 x 4
    const int lrow = l & 15, lk = l >> 4;
    const int bm = blockIdx.x, bn = blockIdx.y;

    // stage B panel: chunk (col, kc) -> LDS chunk index col*32 + (kc ^ (col&7))
    constexpr int CH = BN * 32;
#pragma unroll
    for (int it = 0; it < CH / 512; ++it) {
        int c = it * 512 + tid;
        int col = c >> 5, kc = c & 31;
        bf16x8 v = *(const bf16x8*)(Bt + (size_t)(bn * BN + col) * K + kc * 8);
        *(bf16x8*)(Bs + col * K + ((kc ^ (col & 7)) * 8)) = v;
    }
    __syncthreads();

    f32x4 acc[4][NRF];
#pragma unroll
    for (int m = 0; m < 4; ++m)
#pragma unroll
        for (int n = 0; n < NRF; ++n) acc[m][n] = (f32x4){0.f, 0.f, 0.f, 0.f};

    const u16* Abase = A + (size_t)(bm * 128 + wm * 64 + lrow) * K + lk * 8;

#pragma unroll
    for (int ks = 0; ks < 8; ++ks) {
        bf16x8 av[4], bv[NRF];
#pragma unroll
        for (int m = 0; m < 4; ++m)
            av[m] = *(const bf16x8*)(Abase + (size_t)m * 16 * K + ks * 32);
#pragma unroll
        for (int n = 0; n < NRF; ++n) {
            int col = wn * (NRF * 16) + n * 16 + lrow;
            int kc = ks * 4 + lk;
            bv[n] = *(const bf16x8*)(Bs + col * K + ((kc ^ (col & 7)) * 8));
        }
#pragma unroll
        for (int m = 0; m < 4; ++m)
#pragma unroll
            for (int n = 0; n < NRF; ++n)
                acc[m][n] = __builtin_amdgcn_mfma_f32_16x16x32_bf16(av[m], bv[n], acc[m][n], 0, 0, 0);
    }

    float bl[NRF];
#pragma unroll
    for (int n = 0; n < NRF; ++n) bl[n] = bias[bn * BN + wn * (NRF * 16) + n * 16 + lrow];

#pragma unroll
    for (int m = 0; m < 4; ++m) {
        int grow = bm * 128 + wm * 64 + m * 16 + lk * 4;
#pragma unroll
        for (int j = 0; j < 4; ++j) {
            if (grow + j < M) {
#pragma unroll
                for (int n = 0; n < NRF; ++n) {
                    int col = bn * BN + wn * (NRF * 16) + n * 16 + lrow;
                    float v = acc[m][n][j] + bl[n];
                    if (F32OUT)
                        ((float*)out)[(size_t)(grow + j) * Nout + col] = v;
                    else
                        ((u16*)out)[(size_t)(grow + j) * Nout + col] = f2bf(v);
                }
            }
        }
    }
}

// ---------------- GATv2 edge phase: one wave per destination node, unroll 4 ----------------
// XLR: [Mpad][512] bf16 (cols 0-255 xl, 256-511 xr). lane l: head l>>4, ch (l&15)*4.
// No max subtraction (logits bounded); att pre-scaled by log2(e).

__global__ __launch_bounds__(256) void k_gat_edge(const int* __restrict__ rowptr,
                                                  const int* __restrict__ csr,
                                                  const u16* __restrict__ XLR,
                                                  const float* __restrict__ att,
                                                  const float* __restrict__ bias,
                                                  u16* __restrict__ H, int N) {
    int wid = blockIdx.x * 4 + (threadIdx.x >> 6);
    if (wid >= N) return;
    int l = threadIdx.x & 63;

    const float LOG2E = 1.4426950408889634f;
    float4 a4 = *(const float4*)(att + l * 4);
    a4.x *= LOG2E; a4.y *= LOG2E; a4.z *= LOG2E; a4.w *= LOG2E;

    const char* Xb = (const char*)XLR;
    const unsigned lofs = (unsigned)(l << 3);
    uint2 xr = *(const uint2*)(Xb + (((unsigned)wid << 10) + 512u + lofs));
    float r0 = __uint_as_float(xr.x << 16), r1 = __uint_as_float(xr.x & 0xffff0000u);
    float r2 = __uint_as_float(xr.y << 16), r3 = __uint_as_float(xr.y & 0xffff0000u);

    int beg = rowptr[wid], end = rowptr[wid + 1];
    float s = 0.f, o0 = 0.f, o1 = 0.f, o2 = 0.f, o3 = 0.f;

    auto edge1 = [&](uint2 wv) {
        float c0 = __uint_as_float(wv.x << 16), c1 = __uint_as_float(wv.x & 0xffff0000u);
        float c2 = __uint_as_float(wv.y << 16), c3 = __uint_as_float(wv.y & 0xffff0000u);
        float t0 = c0 + r0, t1 = c1 + r1, t2 = c2 + r2, t3 = c3 + r3;
        t0 = fmaf(-0.8f, fminf(t0, 0.f), t0);
        t1 = fmaf(-0.8f, fminf(t1, 0.f), t1);
        t2 = fmaf(-0.8f, fminf(t2, 0.f), t2);
        t3 = fmaf(-0.8f, fminf(t3, 0.f), t3);
        float p = t0 * a4.x; p = fmaf(t1, a4.y, p); p = fmaf(t2, a4.z, p); p = fmaf(t3, a4.w, p);
        p = dpp_add<0xB1>(p);   // xor1
        p = dpp_add<0x4E>(p);   // xor2
        p = dpp_add<0x141>(p);  // row_half_mirror
        p = dpp_add<0x140>(p);  // row_mirror
        float e = exp2_hw(p);
        s += e;
        o0 = fmaf(e, c0, o0); o1 = fmaf(e, c1, o1);
        o2 = fmaf(e, c2, o2); o3 = fmaf(e, c3, o3);
    };

    int i = beg;
    for (; i + 4 <= end; i += 4) {
        int u0 = csr[i], u1 = csr[i + 1], u2 = csr[i + 2], u3 = csr[i + 3];
        uint2 w0 = *(const uint2*)(Xb + (((unsigned)u0 << 10) + lofs));
        uint2 w1 = *(const uint2*)(Xb + (((unsigned)u1 << 10) + lofs));
        uint2 w2 = *(const uint2*)(Xb + (((unsigned)u2 << 10) + lofs));
        uint2 w3 = *(const uint2*)(Xb + (((unsigned)u3 << 10) + lofs));
        edge1(w0); edge1(w1); edge1(w2); edge1(w3);
    }
    for (; i < end; ++i) {
        int u0 = csr[i];
        uint2 w0 = *(const uint2*)(Xb + (((unsigned)u0 << 10) + lofs));
        edge1(w0);
    }

    float inv = 1.f / s;
    float4 bb = *(const float4*)(bias + l * 4);
    o0 = fmaxf(fmaf(o0, inv, bb.x), 0.f);
    o1 = fmaxf(fmaf(o1, inv, bb.y), 0.f);
    o2 = fmaxf(fmaf(o2, inv, bb.z), 0.f);
    o3 = fmaxf(fmaf(o3, inv, bb.w), 0.f);
    ushort4 w4 = {f2bf(o0), f2bf(o1), f2bf(o2), f2bf(o3)};
    *(ushort4*)(H + (size_t)wid * 256 + l * 4) = w4;
}

// ---------------- launcher ----------------

extern "C" void kernel_launch(void* const* d_in, const int* in_sizes, int n_in,
                              void* d_out, int out_size, void* d_ws, size_t ws_size,
                              hipStream_t stream) {
    const float* x     = (const float*)d_in[0];
    const int*   ei    = (const int*)d_in[1];
    const float* W1l   = (const float*)d_in[2];
    const float* b1l   = (const float*)d_in[3];
    const float* W1r   = (const float*)d_in[4];
    const float* b1r   = (const float*)d_in[5];
    const float* att1  = (const float*)d_in[6];
    const float* bias1 = (const float*)d_in[7];
    const float* W2l   = (const float*)d_in[8];
    const float* b2l   = (const float*)d_in[9];
    const float* W2r   = (const float*)d_in[10];
    const float* b2r   = (const float*)d_in[11];
    const float* att2  = (const float*)d_in[12];
    const float* bias2 = (const float*)d_in[13];
    const float* Wp1   = (const float*)d_in[14];
    const float* bp1   = (const float*)d_in[15];
    const float* Wp2   = (const float*)d_in[16];
    const float* bp2   = (const float*)d_in[17];

    const int N = in_sizes[0] / 256;
    const int E = in_sizes[1] / 2;
    const int EP = E + N;
    const int Mpad = ((N + 127) / 128) * 128;
    const int Mt = Mpad / 128;

    char* ws = (char*)d_ws;
    size_t o = 0;
    auto alloc = [&](size_t b) { char* p = ws + o; o = (o + b + 255) & ~(size_t)255; return p; };
    u16* Abuf   = (u16*)alloc((size_t)Mpad * 256 * 2);  // x_bf -> h1 -> h2
    u16* XLR    = (u16*)alloc((size_t)Mpad * 512 * 2);  // [xl | xr]
    u16* WB1    = (u16*)alloc(512 * 256 * 2);
    u16* WB2    = (u16*)alloc(512 * 256 * 2);
    u16* Wpt    = (u16*)alloc(64 * 256 * 2);
    float* bc1  = (float*)alloc(512 * 4);
    float* bc2  = (float*)alloc(512 * 4);
    float* bpf  = (float*)alloc(64 * 4);
    int* cnt    = (int*)alloc((size_t)N * 4);
    int* rowptr = (int*)alloc((size_t)(N + 1) * 4);
    int* cursor = (int*)alloc((size_t)N * 4);
    int* bsums  = (int*)alloc(64 * 4);
    int* csr    = (int*)alloc((size_t)EP * 4);

    hipMemsetAsync(cnt, 0, (size_t)N * 4, stream);
    if (Mpad > N)
        hipMemsetAsync(Abuf + (size_t)N * 256, 0, (size_t)(Mpad - N) * 256 * 2, stream);

    // fused prep: block ranges
    const int nCvt = (N * 64 + 255) / 256;
    const int nTr = 1024;
    const int nFuse = 64;
    const int nCnt = (EP + 255) / 256;
    const int c0 = nCvt, c1 = c0 + nTr, c2 = c1 + nFuse, c3 = c2 + nCnt, c4 = c3 + 4;
    k_prep<<<c4, 256, 0, stream>>>(x, W1l, W1r, W2l, W2r, b1l, b1r, b2l, b2r,
                                   Wp1, bp1, Wp2, bp2, ei, Abuf, WB1, WB2, bc1, bc2,
                                   Wpt, bpf, cnt, N, E, c0, c1, c2, c3);

    int nb = (N + 1023) / 1024;
    k_scan_block<<<nb, 256, 0, stream>>>(cnt, rowptr, bsums, N);
    k_scan_bsums<<<1, 64, 0, stream>>>(bsums, nb);
    k_finalize<<<(N + 1 + 255) / 256, 256, 0, stream>>>(rowptr, bsums, cursor, N, EP);
    k_scatter<<<nCnt, 256, 0, stream>>>(ei, cursor, csr, E, N);

    dim3 gL(Mt, 2);   // 2 x BN=256 col tiles for 512 cols
    int egrid = (N + 3) / 4;
    // layer 1
    k_gemm_bres<256, 4, false><<<gL, 512, 0, stream>>>(Abuf, WB1, bc1, XLR, N, 512);
    k_gat_edge<<<egrid, 256, 0, stream>>>(rowptr, csr, XLR, att1, bias1, Abuf, N);
    // layer 2
    k_gemm_bres<256, 4, false><<<gL, 512, 0, stream>>>(Abuf, WB2, bc2, XLR, N, 512);
    k_gat_edge<<<egrid, 256, 0, stream>>>(rowptr, csr, XLR, att2, bias2, Abuf, N);
    // fused post-MLP
    dim3 g1(Mt, 1);
    k_gemm_bres<64, 1, true><<<g1, 512, 0, stream>>>(Abuf, Wpt, bpf, d_out, N, 64);
}

// Round 5
// 316.587 us; speedup vs baseline: 1.1430x; 1.1430x over previous
//
#include <hip/hip_runtime.h>

typedef unsigned short u16;
typedef short bf16x8 __attribute__((ext_vector_type(8)));
typedef float f32x4 __attribute__((ext_vector_type(4)));

__device__ __forceinline__ float bf2f(u16 x) { return __uint_as_float(((unsigned)x) << 16); }
__device__ __forceinline__ u16 f2bf(float f) {
    unsigned u = __float_as_uint(f);
    return (u16)((u + 0x7fffu + ((u >> 16) & 1u)) >> 16);
}
__device__ __forceinline__ float exp2_hw(float x) {
    float r;
    asm("v_exp_f32 %0, %1" : "=v"(r) : "v"(x));
    return r;
}
template <int CTRL>
__device__ __forceinline__ float dpp_add(float p) {
    int t = __builtin_amdgcn_update_dpp(0, __float_as_int(p), CTRL, 0xf, 0xf, true);
    return p + __int_as_float(t);
}
__device__ __forceinline__ void gload_lds16(const u16* g, u16* lds) {
    __builtin_amdgcn_global_load_lds((const __attribute__((address_space(1))) void*)g,
                                     (__attribute__((address_space(3))) void*)lds, 16, 0, 0);
}

// ---------------- fused prep kernel ----------------
// block ranges: [0,c0) weight transpose; [c0,c1) post-MLP fuse; [c1,c2) edge count;
// [c2,c2+4) bias concat.

__global__ __launch_bounds__(256) void k_prep(const float* __restrict__ W1l, const float* __restrict__ W1r,
                                              const float* __restrict__ W2l, const float* __restrict__ W2r,
                                              const float* __restrict__ b1l, const float* __restrict__ b1r,
                                              const float* __restrict__ b2l, const float* __restrict__ b2r,
                                              const float* __restrict__ Wp1, const float* __restrict__ bp1,
                                              const float* __restrict__ Wp2, const float* __restrict__ bp2,
                                              const int* __restrict__ ei,
                                              u16* __restrict__ WB1, u16* __restrict__ WB2,
                                              float* __restrict__ bc1, float* __restrict__ bc2,
                                              u16* __restrict__ Wpt, float* __restrict__ bpf,
                                              int* __restrict__ cnt,
                                              int N, int E, int c0, int c1, int c2) {
    int b = blockIdx.x;
    int tid = threadIdx.x;
    if (b < c0) {  // weight transpose: WB = [Wl^T ; Wr^T] bf16
        int n = b & 255, m = b >> 8;
        const float* W = (m == 0) ? W1l : (m == 1) ? W1r : (m == 2) ? W2l : W2r;
        u16* dst = (m < 2) ? WB1 : WB2;
        dst[(size_t)((m & 1) * 256 + n) * 256 + tid] = f2bf(W[(size_t)tid * 256 + n]);
    } else if (b < c1) {  // fused post-MLP weight
        int j = b - c0;
        float a = 0.f;
        for (int k = 0; k < 64; ++k) a += Wp1[tid * 64 + k] * Wp2[k * 64 + j];
        Wpt[j * 256 + tid] = f2bf(a);
        if (tid == 0) {
            float bb = bp2[j];
            for (int k = 0; k < 64; ++k) bb += bp1[k] * Wp2[k * 64 + j];
            bpf[j] = bb;
        }
    } else if (b < c2) {  // degree count
        int e = (b - c1) * 256 + tid;
        if (e < E + N) {
            int dst = (e < E) ? ei[E + e] : (e - E);
            atomicAdd(cnt + dst, 1);
        }
    } else {  // bias concat
        int m = b - c2;
        const float* s = (m == 0) ? b1l : (m == 1) ? b1r : (m == 2) ? b2l : b2r;
        float* d = (m < 2) ? bc1 : bc2;
        d[(m & 1) * 256 + tid] = s[tid];
    }
}

// ---------------- CSR build ----------------

__global__ __launch_bounds__(256) void k_scan_block(const int* __restrict__ cnt,
                                                    int* __restrict__ rowptr,
                                                    int* __restrict__ bsums, int N) {
    __shared__ int sd[256];
    int tid = threadIdx.x;
    int base = blockIdx.x * 1024 + tid * 4;
    int v0 = (base + 0 < N) ? cnt[base + 0] : 0;
    int v1 = (base + 1 < N) ? cnt[base + 1] : 0;
    int v2 = (base + 2 < N) ? cnt[base + 2] : 0;
    int v3 = (base + 3 < N) ? cnt[base + 3] : 0;
    int ts = v0 + v1 + v2 + v3;
    sd[tid] = ts;
    __syncthreads();
    for (int ofs = 1; ofs < 256; ofs <<= 1) {
        int t = (tid >= ofs) ? sd[tid - ofs] : 0;
        __syncthreads();
        sd[tid] += t;
        __syncthreads();
    }
    int excl = sd[tid] - ts;
    if (base + 0 < N) rowptr[base + 0] = excl;
    if (base + 1 < N) rowptr[base + 1] = excl + v0;
    if (base + 2 < N) rowptr[base + 2] = excl + v0 + v1;
    if (base + 3 < N) rowptr[base + 3] = excl + v0 + v1 + v2;
    if (tid == 255) bsums[blockIdx.x] = sd[255];
}

__global__ void k_scan_bsums(int* __restrict__ bsums, int nb) {
    int l = threadIdx.x;
    int v = (l < nb) ? bsums[l] : 0;
    int x = v;
    for (int ofs = 1; ofs < 64; ofs <<= 1) {
        int t = __shfl_up(x, ofs);
        if (l >= ofs) x += t;
    }
    if (l < nb) bsums[l] = x - v;
}

__global__ __launch_bounds__(256) void k_finalize(int* __restrict__ rowptr,
                                                  const int* __restrict__ bscan,
                                                  int* __restrict__ cursor, int N, int EP) {
    int i = blockIdx.x * 256 + threadIdx.x;
    if (i < N) {
        int v = rowptr[i] + bscan[i >> 10];
        rowptr[i] = v;
        cursor[i] = v;
    } else if (i == N) {
        rowptr[N] = EP;
    }
}

__global__ __launch_bounds__(256) void k_scatter(const int* __restrict__ ei,
                                                 int* __restrict__ cursor,
                                                 int* __restrict__ csr, int E, int N) {
    int e = blockIdx.x * 256 + threadIdx.x;
    if (e < E + N) {
        int src, dst;
        if (e < E) { src = ei[e]; dst = ei[E + e]; }
        else       { src = e - E; dst = e - E; }
        int p = atomicAdd(cursor + dst, 1);
        csr[p] = src;
    }
}

// ---------------- hybrid MFMA GEMM ----------------
// C[M,Nout] = A[M,256] @ Bt^T + bias.  Bt:[Nout][256] bf16.
// B panel (BN x 256) LDS-resident full-K (staged once, XOR chunk swizzle).
// A staged per BK=64 step via coalesced LDS path (global_load_lds for bf16;
// reg-stage+cvt for f32). 8 waves (2x4), wave tile 64 x (NRF*16), NRF=BN/64.
// LDS = BN*512 + 16KB: BN=128 -> 80KB (2 blocks/CU), BN=64 -> 48KB (3 blocks/CU).

template <int BN, bool AF32, bool F32OUT>
__global__ __launch_bounds__(512) void k_gemm_hyb(const void* __restrict__ Av,
                                                  const u16* __restrict__ Bt,
                                                  const float* __restrict__ bias,
                                                  void* __restrict__ out, int M, int Nout) {
    constexpr int K = 256;
    constexpr int NRF = BN / 64;
    __shared__ __align__(16) u16 Bs[BN * K];
    __shared__ __align__(16) u16 As[128 * 64];
    const int tid = threadIdx.x;
    const int l = tid & 63;
    const int w = tid >> 6;
    const int wm = w >> 2, wn = w & 3;
    const int lrow = l & 15, lk = l >> 4;
    const int bm = blockIdx.x, bn = blockIdx.y;
    const int wbase = tid & ~63;

    // ---- stage B panel once ----
#pragma unroll
    for (int it = 0; it < BN / 16; ++it) {
        int c = it * 512 + tid;
        int col = c >> 5, kc = c & 31;
        bf16x8 v = *(const bf16x8*)(Bt + (size_t)(bn * BN + col) * K + kc * 8);
        *(bf16x8*)(Bs + col * K + ((kc ^ (col & 7)) * 8)) = v;
    }

    auto stageA = [&](int ks) {
        if (AF32) {
            const float* A32 = (const float*)Av;
#pragma unroll
            for (int it = 0; it < 2; ++it) {
                int c = it * 512 + tid;
                int row = c >> 3, seg = c & 7;
                int grow = bm * 128 + row;
                if (grow > M - 1) grow = M - 1;
                const float* s = A32 + (size_t)grow * K + ks * 64 + seg * 8;
                float4 v0 = *(const float4*)s;
                float4 v1 = *(const float4*)(s + 4);
                bf16x8 pk;
                pk[0] = (short)f2bf(v0.x); pk[1] = (short)f2bf(v0.y);
                pk[2] = (short)f2bf(v0.z); pk[3] = (short)f2bf(v0.w);
                pk[4] = (short)f2bf(v1.x); pk[5] = (short)f2bf(v1.y);
                pk[6] = (short)f2bf(v1.z); pk[7] = (short)f2bf(v1.w);
                *(bf16x8*)(As + row * 64 + ((seg ^ (row & 7)) * 8)) = pk;
            }
        } else {
            const u16* Abf = (const u16*)Av;
#pragma unroll
            for (int it = 0; it < 2; ++it) {
                int c = it * 512 + tid;
                int row = c >> 3, seg = c & 7;
                int ssrc = seg ^ (row & 7);
                gload_lds16(Abf + (size_t)(bm * 128 + row) * K + ks * 64 + ssrc * 8,
                            As + (size_t)(it * 512 + wbase) * 8);
            }
        }
    };

    f32x4 acc[4][NRF];
#pragma unroll
    for (int m = 0; m < 4; ++m)
#pragma unroll
        for (int n = 0; n < NRF; ++n) acc[m][n] = (f32x4){0.f, 0.f, 0.f, 0.f};

    stageA(0);
    __syncthreads();

    for (int ks = 0; ks < 4; ++ks) {
#pragma unroll
        for (int h = 0; h < 2; ++h) {
            bf16x8 av[4], bv[NRF];
#pragma unroll
            for (int m = 0; m < 4; ++m) {
                int row = wm * 64 + m * 16 + lrow;
                int seg = ((h * 4 + lk) ^ (row & 7));
                av[m] = *(const bf16x8*)(As + row * 64 + seg * 8);
            }
#pragma unroll
            for (int n = 0; n < NRF; ++n) {
                int col = wn * (NRF * 16) + n * 16 + lrow;
                int kc = ks * 8 + h * 4 + lk;
                bv[n] = *(const bf16x8*)(Bs + col * K + ((kc ^ (col & 7)) * 8));
            }
#pragma unroll
            for (int m = 0; m < 4; ++m)
#pragma unroll
                for (int n = 0; n < NRF; ++n)
                    acc[m][n] = __builtin_amdgcn_mfma_f32_16x16x32_bf16(av[m], bv[n], acc[m][n], 0, 0, 0);
        }
        if (ks < 3) {
            __syncthreads();      // all reads of As done
            stageA(ks + 1);
            __syncthreads();      // As restaged
        }
    }

    float bl[NRF];
#pragma unroll
    for (int n = 0; n < NRF; ++n) bl[n] = bias[bn * BN + wn * (NRF * 16) + n * 16 + lrow];

#pragma unroll
    for (int m = 0; m < 4; ++m) {
        int grow = bm * 128 + wm * 64 + m * 16 + lk * 4;
#pragma unroll
        for (int j = 0; j < 4; ++j) {
            if (grow + j < M) {
#pragma unroll
                for (int n = 0; n < NRF; ++n) {
                    int col = bn * BN + wn * (NRF * 16) + n * 16 + lrow;
                    float v = acc[m][n][j] + bl[n];
                    if (F32OUT)
                        ((float*)out)[(size_t)(grow + j) * Nout + col] = v;
                    else
                        ((u16*)out)[(size_t)(grow + j) * Nout + col] = f2bf(v);
                }
            }
        }
    }
}

// ---------------- GATv2 edge phase: one wave per destination node ----------------
// Scalar (SGPR) addressing: wid and csr values forced to SGPR via readfirstlane ->
// gather loads are saddr-form, minimal VALU address math.

__global__ __launch_bounds__(256) void k_gat_edge(const int* __restrict__ rowptr,
                                                  const int* __restrict__ csr,
                                                  const u16* __restrict__ XLR,
                                                  const float* __restrict__ att,
                                                  const float* __restrict__ bias,
                                                  u16* __restrict__ H, int N) {
    int wid0 = blockIdx.x * 4 + (threadIdx.x >> 6);
    if (wid0 >= N) return;
    const int wid = __builtin_amdgcn_readfirstlane(wid0);
    int l = threadIdx.x & 63;

    const float LOG2E = 1.4426950408889634f;
    float4 a4 = *(const float4*)(att + l * 4);
    a4.x *= LOG2E; a4.y *= LOG2E; a4.z *= LOG2E; a4.w *= LOG2E;

    const char* Xb = (const char*)XLR;
    const int lofs = l << 3;
    uint2 xr = *(const uint2*)(Xb + ((size_t)wid << 10) + 512 + lofs);
    float r0 = __uint_as_float(xr.x << 16), r1 = __uint_as_float(xr.x & 0xffff0000u);
    float r2 = __uint_as_float(xr.y << 16), r3 = __uint_as_float(xr.y & 0xffff0000u);

    int beg = rowptr[wid], end = rowptr[wid + 1];
    float s = 0.f, o0 = 0.f, o1 = 0.f, o2 = 0.f, o3 = 0.f;

    auto edge1 = [&](uint2 wv) {
        float c0 = __uint_as_float(wv.x << 16), c1 = __uint_as_float(wv.x & 0xffff0000u);
        float c2 = __uint_as_float(wv.y << 16), c3 = __uint_as_float(wv.y & 0xffff0000u);
        float t0 = c0 + r0, t1 = c1 + r1, t2 = c2 + r2, t3 = c3 + r3;
        t0 = fmaf(-0.8f, fminf(t0, 0.f), t0);
        t1 = fmaf(-0.8f, fminf(t1, 0.f), t1);
        t2 = fmaf(-0.8f, fminf(t2, 0.f), t2);
        t3 = fmaf(-0.8f, fminf(t3, 0.f), t3);
        float p = t0 * a4.x; p = fmaf(t1, a4.y, p); p = fmaf(t2, a4.z, p); p = fmaf(t3, a4.w, p);
        p = dpp_add<0xB1>(p);   // xor1
        p = dpp_add<0x4E>(p);   // xor2
        p = dpp_add<0x141>(p);  // row_half_mirror
        p = dpp_add<0x140>(p);  // row_mirror
        float e = exp2_hw(p);
        s += e;
        o0 = fmaf(e, c0, o0); o1 = fmaf(e, c1, o1);
        o2 = fmaf(e, c2, o2); o3 = fmaf(e, c3, o3);
    };

    int i = beg;
    for (; i + 4 <= end; i += 4) {
        int u0 = __builtin_amdgcn_readfirstlane(csr[i]);
        int u1 = __builtin_amdgcn_readfirstlane(csr[i + 1]);
        int u2 = __builtin_amdgcn_readfirstlane(csr[i + 2]);
        int u3 = __builtin_amdgcn_readfirstlane(csr[i + 3]);
        uint2 w0 = *(const uint2*)(Xb + ((size_t)u0 << 10) + lofs);
        uint2 w1 = *(const uint2*)(Xb + ((size_t)u1 << 10) + lofs);
        uint2 w2 = *(const uint2*)(Xb + ((size_t)u2 << 10) + lofs);
        uint2 w3 = *(const uint2*)(Xb + ((size_t)u3 << 10) + lofs);
        edge1(w0); edge1(w1); edge1(w2); edge1(w3);
    }
    for (; i < end; ++i) {
        int u0 = __builtin_amdgcn_readfirstlane(csr[i]);
        uint2 w0 = *(const uint2*)(Xb + ((size_t)u0 << 10) + lofs);
        edge1(w0);
    }

    float inv = 1.f / s;
    float4 bb = *(const float4*)(bias + l * 4);
    o0 = fmaxf(fmaf(o0, inv, bb.x), 0.f);
    o1 = fmaxf(fmaf(o1, inv, bb.y), 0.f);
    o2 = fmaxf(fmaf(o2, inv, bb.z), 0.f);
    o3 = fmaxf(fmaf(o3, inv, bb.w), 0.f);
    ushort4 w4 = {f2bf(o0), f2bf(o1), f2bf(o2), f2bf(o3)};
    *(ushort4*)(H + ((size_t)wid << 8) + l * 4) = w4;
}

// ---------------- launcher ----------------

extern "C" void kernel_launch(void* const* d_in, const int* in_sizes, int n_in,
                              void* d_out, int out_size, void* d_ws, size_t ws_size,
                              hipStream_t stream) {
    const float* x     = (const float*)d_in[0];
    const int*   ei    = (const int*)d_in[1];
    const float* W1l   = (const float*)d_in[2];
    const float* b1l   = (const float*)d_in[3];
    const float* W1r   = (const float*)d_in[4];
    const float* b1r   = (const float*)d_in[5];
    const float* att1  = (const float*)d_in[6];
    const float* bias1 = (const float*)d_in[7];
    const float* W2l   = (const float*)d_in[8];
    const float* b2l   = (const float*)d_in[9];
    const float* W2r   = (const float*)d_in[10];
    const float* b2r   = (const float*)d_in[11];
    const float* att2  = (const float*)d_in[12];
    const float* bias2 = (const float*)d_in[13];
    const float* Wp1   = (const float*)d_in[14];
    const float* bp1   = (const float*)d_in[15];
    const float* Wp2   = (const float*)d_in[16];
    const float* bp2   = (const float*)d_in[17];

    const int N = in_sizes[0] / 256;
    const int E = in_sizes[1] / 2;
    const int EP = E + N;
    const int Mpad = ((N + 127) / 128) * 128;
    const int Mt = Mpad / 128;

    char* ws = (char*)d_ws;
    size_t o = 0;
    auto alloc = [&](size_t b) { char* p = ws + o; o = (o + b + 255) & ~(size_t)255; return p; };
    u16* Abuf   = (u16*)alloc((size_t)Mpad * 256 * 2);  // h1 -> h2
    u16* XLR    = (u16*)alloc((size_t)Mpad * 512 * 2);  // [xl | xr]
    u16* WB1    = (u16*)alloc(512 * 256 * 2);
    u16* WB2    = (u16*)alloc(512 * 256 * 2);
    u16* Wpt    = (u16*)alloc(64 * 256 * 2);
    float* bc1  = (float*)alloc(512 * 4);
    float* bc2  = (float*)alloc(512 * 4);
    float* bpf  = (float*)alloc(64 * 4);
    int* cnt    = (int*)alloc((size_t)N * 4);
    int* rowptr = (int*)alloc((size_t)(N + 1) * 4);
    int* cursor = (int*)alloc((size_t)N * 4);
    int* bsums  = (int*)alloc(64 * 4);
    int* csr    = (int*)alloc((size_t)EP * 4);

    hipMemsetAsync(cnt, 0, (size_t)N * 4, stream);
    if (Mpad > N)  // pad rows of Abuf must be finite for layer-2/post GEMM reads
        hipMemsetAsync(Abuf + (size_t)N * 256, 0, (size_t)(Mpad - N) * 256 * 2, stream);

    // fused prep: [0,1024) transpose, [1024,1088) post fuse, [1088,1088+nCnt) count, +4 bias
    const int nCnt = (EP + 255) / 256;
    const int c0 = 1024, c1 = c0 + 64, c2 = c1 + nCnt, cT = c2 + 4;
    k_prep<<<cT, 256, 0, stream>>>(W1l, W1r, W2l, W2r, b1l, b1r, b2l, b2r,
                                   Wp1, bp1, Wp2, bp2, ei, WB1, WB2, bc1, bc2,
                                   Wpt, bpf, cnt, N, E, c0, c1, c2);

    int nb = (N + 1023) / 1024;
    k_scan_block<<<nb, 256, 0, stream>>>(cnt, rowptr, bsums, N);
    k_scan_bsums<<<1, 64, 0, stream>>>(bsums, nb);
    k_finalize<<<(N + 1 + 255) / 256, 256, 0, stream>>>(rowptr, bsums, cursor, N, EP);
    k_scatter<<<nCnt, 256, 0, stream>>>(ei, cursor, csr, E, N);

    dim3 gL(Mt, 4);  // 4 x BN=128 col tiles for 512 cols
    int egrid = (N + 3) / 4;
    // layer 1 (A = x in f32, converted during staging)
    k_gemm_hyb<128, true, false><<<gL, 512, 0, stream>>>(x, WB1, bc1, XLR, N, 512);
    k_gat_edge<<<egrid, 256, 0, stream>>>(rowptr, csr, XLR, att1, bias1, Abuf, N);
    // layer 2
    k_gemm_hyb<128, false, false><<<gL, 512, 0, stream>>>(Abuf, WB2, bc2, XLR, N, 512);
    k_gat_edge<<<egrid, 256, 0, stream>>>(rowptr, csr, XLR, att2, bias2, Abuf, N);
    // fused post-MLP
    dim3 g1(Mt, 1);
    k_gemm_hyb<64, false, true><<<g1, 512, 0, stream>>>(Abuf, Wpt, bpf, d_out, N, 64);
}